// Round 11
// baseline (147.379 us; speedup 1.0000x reference)
//
#include <hip/hip_runtime.h>

#define EPS 1e-7f
#define LOG2E 1.44269504088896340736f

constexpr int BLOCK = 256;   // 4 waves; thread = one j
constexpr int JG_SZ = 256;   // j's per group (= BLOCK)
constexpr int NS    = 32;    // N-slices per j-group

// j-per-lane, points wave-uniform. R10 post-mortem: all prior structures are
// VALU-issue-bound on OVERHEAD (scalarized f32x2 math, ds addr calc, unpack,
// staging) -- VALUBusy*dur = ~21k cyc/SIMD vs ~6k of core math. Here each
// thread owns ONE j (4 coeff VGPRs); the point loop index is wave-uniform so
// inputs[p]/outputs[p] become scalar (SMEM) loads: per point 6 v_fma-class
// + 1 v_exp, 64 evals/issue -- no LDS, no barriers, no unpack, no staging.
// Cross-block combine: device-scope atomicAdd partials in d_ws (zeroed via
// hipMemsetAsync each launch) + per-group completion counter; last block of
// each group finalizes its 256 outputs. No spin-waits -> no deadlock.
__global__ __launch_bounds__(BLOCK, 4) void nw_block(
    const float2* __restrict__ x,        // M x 2 query points
    const float2* __restrict__ inputs,   // N x 2 data points
    const float*  __restrict__ outputs,  // N
    const float*  __restrict__ bw,       // M
    float*        __restrict__ out,      // M
    float*        __restrict__ wsn,      // M partial numerators
    float*        __restrict__ wsd,      // M partial denominators
    int*          __restrict__ cnt,      // JG completion counters
    int N, int M, int JG, int PPS)
{
    __shared__ int lastFlag;

    const int tid = threadIdx.x;
    const int g   = blockIdx.x % JG;     // j-group
    const int s   = blockIdx.x / JG;     // N-slice
    const int j   = g * JG_SZ + tid;

    // per-thread coefficients: t = c0*(px^2+py^2) + c1*px + c2*py + c3, k<0 folded
    float c0 = 0.f, c1 = 0.f, c2 = 0.f, c3 = 0.f;
    if (j < M) {
        float2 xj = x[j];
        float  b  = bw[j];
        float  k  = -LOG2E / (2.0f * b * b);     // < 0 (b >= 0.5)
        c0 = k;
        c1 = -2.0f * k * xj.x;
        c2 = -2.0f * k * xj.y;
        c3 = k * fmaf(xj.x, xj.x, xj.y * xj.y);
    }

    const int p0 = s * PPS;
    const int p1 = min(p0 + PPS, N);

    float num = 0.f, den = 0.f;
    #pragma unroll 8
    for (int p = p0; p < p1; ++p) {
        const float2 pt = inputs[p];     // wave-uniform -> s_load (SMEM pipe)
        const float  o  = outputs[p];    // wave-uniform -> s_load
        // t = c0*(x^2+y^2) + c1*x + c2*y + c3, s-free 4-fma form
        const float A = fmaf(c0, pt.x, c1);
        const float B = fmaf(c0, pt.y, c2);
        const float t = fmaf(A, pt.x, fmaf(B, pt.y, c3));
        const float w = __builtin_amdgcn_exp2f(t);
        num = fmaf(w, o, num);
        den += w;
    }

    if (j < M) {
        atomicAdd(&wsn[j], num);         // device-scope (m20)
        atomicAdd(&wsd[j], den);
    }
    __threadfence();                     // release our adds (agent scope)
    __syncthreads();                     // all threads' adds+fence done

    if (tid == 0) {
        const int old = __hip_atomic_fetch_add(cnt + g, 1, __ATOMIC_ACQ_REL,
                                               __HIP_MEMORY_SCOPE_AGENT);
        lastFlag = (old == NS - 1);
    }
    __syncthreads();

    if (lastFlag && j < M) {             // last block of group g finalizes its j's
        const float n = __hip_atomic_load(&wsn[j], __ATOMIC_RELAXED,
                                          __HIP_MEMORY_SCOPE_AGENT);
        const float d = __hip_atomic_load(&wsd[j], __ATOMIC_RELAXED,
                                          __HIP_MEMORY_SCOPE_AGENT);
        out[j] = n / (d + EPS);
    }
}

extern "C" void kernel_launch(void* const* d_in, const int* in_sizes, int n_in,
                              void* d_out, int out_size, void* d_ws, size_t ws_size,
                              hipStream_t stream) {
    // setup_inputs() dict order: x (M*2), inputs (N*2), outputs (N), bandwidth (M)
    const float2* x       = (const float2*)d_in[0];
    const float2* inputs  = (const float2*)d_in[1];
    const float*  outputs = (const float*) d_in[2];
    const float*  bwv     = (const float*) d_in[3];
    const int N = in_sizes[2];   // outputs element count
    const int M = in_sizes[3];   // bandwidth element count
    float*        out     = (float*)d_out;

    const int JG  = (M + JG_SZ - 1) / JG_SZ;     // 32 j-groups @ M=8192
    const int PPS = (N + NS - 1) / NS;           // 256 points per slice @ N=8192

    float* wsn = (float*)d_ws;
    float* wsd = wsn + M;
    int*   cnt = (int*)(wsd + M);

    // zero partials + counters each replay (graph-capturable, same as harness fills)
    hipMemsetAsync(d_ws, 0, (size_t)(2 * M) * sizeof(float) + (size_t)JG * sizeof(int),
                   stream);

    dim3 grid(JG * NS);                          // 1024 blocks @ 8192x8192
    nw_block<<<grid, BLOCK, 0, stream>>>(x, inputs, outputs, bwv, out,
                                         wsn, wsd, cnt, N, M, JG, PPS);
}

// Round 13
// 78.967 us; speedup vs baseline: 1.8663x; 1.8663x over previous
//
#include <hip/hip_runtime.h>

#define EPS 1e-7f
#define LOG2E 1.44269504088896340736f

typedef float f32x2 __attribute__((ext_vector_type(2)));
typedef float f32x4 __attribute__((ext_vector_type(4)));

constexpr int BLOCK = 1024;        // 16 waves/block; grid 512 -> 2 blocks/CU = 32 waves/CU
constexpr int JJ    = 4;           // lane-fast j slots
constexpr int JR    = 4;           // j's per thread -> 4 evals per LDS read
constexpr int JB    = JJ * JR;     // 16 outputs per block
constexpr int SS    = BLOCK / JJ;  // 256 i-segments per block
constexpr int CHUNK = 1024;        // points per LDS chunk
constexpr int PTS   = CHUNK / SS;  // 4 points per segment (one b128 group)
constexpr int ROW   = 12;          // 48B rows: 16B-aligned b128, uniform 2-way banks (free)
constexpr int WAVES = BLOCK / 64;

// R9 math verbatim (builtin f32x2 fma -- pk-asm closed after 2 correctness
// failures), ONE lever: occupancy 16 -> 32 waves/CU. BLOCK=1024 at same
// JB=16 keeps grid 512 = 2 blocks/CU. Per-eval instr count and total LDS
// traffic (1024 b128/CU) unchanged; only waves/SIMD doubles (4 -> 8) to
// hide the t->exp->acc chain + LDS latency (R4: VALUBusy 60%, ~6us of
// bubbles). Cross-segment reduction in-wave via shfl_down so red shrinks
// 32KB -> 2KB; LDS/block = 51.2KB, 2 blocks = 102.4KB < 160. (1024,2)
// caps VGPR at 64; R4 measured 56 for identical register state.
__global__ __launch_bounds__(BLOCK, 2) void nw_block(
    const float2* __restrict__ x,        // M x 2 query points
    const float2* __restrict__ inputs,   // N x 2 data points
    const float*  __restrict__ outputs,  // N
    const float*  __restrict__ bw,       // M
    float*        __restrict__ out,      // M
    int N, int M)
{
    __shared__ __align__(16) float sX[SS][ROW];
    __shared__ __align__(16) float sY[SS][ROW];
    __shared__ __align__(16) float sS[SS][ROW];
    __shared__ __align__(16) float sO[SS][ROW];   // 49.2 KB
    __shared__ float2 red[WAVES][JB];             // 2 KB

    const int tid  = threadIdx.x;
    const int jj   = tid & (JJ - 1);
    const int ss   = tid >> 2;           // tid / JJ
    const int wid  = tid >> 6;
    const int lane = tid & 63;
    const int j0   = blockIdx.x * JB;

    // per-thread coefficient pairs (splat): t = c0*s + c1*px + c2*py + c3, k<0 folded
    f32x2 c0p[JR], c1p[JR], c2p[JR], c3p[JR];
    #pragma unroll
    for (int r = 0; r < JR; ++r) {
        const int j = j0 + jj + r * JJ;
        float k = 0.f, v1 = 0.f, v2 = 0.f, v3 = 0.f;
        if (j < M) {
            float2 xj = x[j];
            float  b  = bw[j];
            k  = -LOG2E / (2.0f * b * b);              // < 0 (b >= 0.5)
            v1 = -2.0f * k * xj.x;
            v2 = -2.0f * k * xj.y;
            v3 = k * fmaf(xj.x, xj.x, xj.y * xj.y);
        }
        c0p[r] = {k, k}; c1p[r] = {v1, v1}; c2p[r] = {v2, v2}; c3p[r] = {v3, v3};
    }

    f32x2 nump[JR], denp[JR];
    #pragma unroll
    for (int r = 0; r < JR; ++r) { nump[r] = {0.f, 0.f}; denp[r] = {0.f, 0.f}; }

    // register prefetch of chunk 0: thread t owns point t
    float2 pin = make_float2(0.f, 0.f);
    float  po  = 0.f;
    if (tid < N) { pin = inputs[tid]; po = outputs[tid]; }

    for (int base = 0; base < N; base += CHUNK) {
        // stage point (base+tid) -> row tid>>2, col tid&3 (b32 writes, 2-way banks = free)
        {
            const bool v = (base + tid) < N;
            sX[ss][jj] = v ? pin.x : 0.f;
            sY[ss][jj] = v ? pin.y : 0.f;
            sS[ss][jj] = v ? fmaf(pin.x, pin.x, pin.y * pin.y) : 3.0e38f;  // c0*s -> -inf -> w=0
            sO[ss][jj] = v ? po    : 0.f;
        }
        __syncthreads();

        // prefetch next chunk; flies under the compute below
        {
            const int nb = base + CHUNK;
            const int gi = nb + tid;
            if (nb < N && gi < N) { pin = inputs[gi]; po = outputs[gi]; }
        }

        // compute: this segment's 4 points (one b128 group per array) x JR j's
        {
            const f32x4 xq = *(const f32x4*)&sX[ss][0];   // ds_read_b128, 2-way = free
            const f32x4 yq = *(const f32x4*)&sY[ss][0];
            const f32x4 sq = *(const f32x4*)&sS[ss][0];
            const f32x4 oq = *(const f32x4*)&sO[ss][0];
            const f32x2 x0 = {xq.x, xq.y}, x1 = {xq.z, xq.w};
            const f32x2 y0 = {yq.x, yq.y}, y1 = {yq.z, yq.w};
            const f32x2 s0 = {sq.x, sq.y}, s1 = {sq.z, sq.w};
            const f32x2 o0 = {oq.x, oq.y}, o1 = {oq.z, oq.w};
            #pragma unroll
            for (int r = 0; r < JR; ++r) {
                f32x2 ta = __builtin_elementwise_fma(c2p[r], y0, c3p[r]);
                ta = __builtin_elementwise_fma(c1p[r], x0, ta);
                ta = __builtin_elementwise_fma(c0p[r], s0, ta);
                f32x2 tb = __builtin_elementwise_fma(c2p[r], y1, c3p[r]);
                tb = __builtin_elementwise_fma(c1p[r], x1, tb);
                tb = __builtin_elementwise_fma(c0p[r], s1, tb);
                f32x2 wa, wb;
                wa.x = __builtin_amdgcn_exp2f(ta.x);
                wa.y = __builtin_amdgcn_exp2f(ta.y);
                wb.x = __builtin_amdgcn_exp2f(tb.x);
                wb.y = __builtin_amdgcn_exp2f(tb.y);
                nump[r] = __builtin_elementwise_fma(wa, o0, nump[r]);
                nump[r] = __builtin_elementwise_fma(wb, o1, nump[r]);
                denp[r] += wa + wb;
            }
        }
        __syncthreads();
    }

    // in-wave cross-segment reduction: lanes share jj when offset is a multiple of 4
    #pragma unroll
    for (int r = 0; r < JR; ++r) {
        float n = nump[r].x + nump[r].y;
        float d = denp[r].x + denp[r].y;
        #pragma unroll
        for (int off = 4; off < 64; off <<= 1) {
            n += __shfl_down(n, off);
            d += __shfl_down(d, off);
        }
        if (lane < JJ)                    // lane == jj
            red[wid][jj + r * JJ] = make_float2(n, d);
    }
    __syncthreads();
    if (tid < JB) {                       // final: 16 threads sum 16 waves
        float n = 0.f, d = 0.f;
        #pragma unroll
        for (int w = 0; w < WAVES; ++w) {
            n += red[w][tid].x;
            d += red[w][tid].y;
        }
        const int j = j0 + tid;
        if (j < M) out[j] = n / (d + EPS);
    }
}

extern "C" void kernel_launch(void* const* d_in, const int* in_sizes, int n_in,
                              void* d_out, int out_size, void* d_ws, size_t ws_size,
                              hipStream_t stream) {
    // setup_inputs() dict order: x (M*2), inputs (N*2), outputs (N), bandwidth (M)
    const float2* x       = (const float2*)d_in[0];
    const float2* inputs  = (const float2*)d_in[1];
    const float*  outputs = (const float*) d_in[2];
    const float*  bwv     = (const float*) d_in[3];
    const int N = in_sizes[2];   // outputs element count
    const int M = in_sizes[3];   // bandwidth element count
    float*        out     = (float*)d_out;

    dim3 grid((M + JB - 1) / JB);    // 512 blocks @ M=8192 -> 2 blocks/CU, 32 waves/CU
    nw_block<<<grid, BLOCK, 0, stream>>>(x, inputs, outputs, bwv, out, N, M);
}

// Round 14
// 72.787 us; speedup vs baseline: 2.0248x; 1.0849x over previous
//
#include <hip/hip_runtime.h>

#define EPS 1e-7f
#define LOG2E 1.44269504088896340736f

typedef float f32x2 __attribute__((ext_vector_type(2)));
typedef float f32x4 __attribute__((ext_vector_type(4)));

constexpr int BLOCK = 512;         // 8 waves/block, 2 blocks/CU
constexpr int JJ    = 4;           // lane-fast j slots
constexpr int JR    = 4;           // j's per thread -> 4 evals per LDS read
constexpr int JB    = JJ * JR;     // 16 outputs per block
constexpr int SS    = BLOCK / JJ;  // 128 i-segments per block
constexpr int CHUNK = 1024;        // points per LDS chunk
constexpr int PTS   = CHUNK / SS;  // 8 points per segment
constexpr int ROW   = 12;          // 12-float rows: 16B-aligned b128, uniform 2-way banks (free)
constexpr int REPS  = 1;

// TERMINAL: session-best configuration (R9, 72.94us total = ~58.2us fixed
// harness floor + 14.7us kernel). Kernel is issue-port-bound: VALU issue
// ~21k cyc/SIMD (= scalarized static count) + ~8.2k trans ~= 83% of the
// cycle budget (R4 counters). Occupancy x2 regressed twice (R10, R13);
// packed-fp32 asm closed after two correctness failures (R2, R12); LDS
// traffic, barriers, residency all proven non-binding (R8==R9). Remaining
// headroom <= ~3% of total, within harness noise.
__global__ __launch_bounds__(BLOCK, 4) void nw_block(
    const float2* __restrict__ x,        // M x 2 query points
    const float2* __restrict__ inputs,   // N x 2 data points
    const float*  __restrict__ outputs,  // N
    const float*  __restrict__ bw,       // M
    float*        __restrict__ out,      // M
    int N, int M)
{
    __shared__ __align__(16) float sX[SS][ROW];
    __shared__ __align__(16) float sY[SS][ROW];
    __shared__ __align__(16) float sS[SS][ROW];
    __shared__ __align__(16) float sO[SS][ROW];
    __shared__ float2 red[SS][JB];       // 16 KB

    const int tid = threadIdx.x;
    const int jj  = tid & (JJ - 1);
    const int ss  = tid >> 2;            // tid / JJ

    // per-thread coefficient pairs (splat): t = c0*s + c1*px + c2*py + c3, k<0 folded
    f32x2 c0p[JR], c1p[JR], c2p[JR], c3p[JR];
    #pragma unroll
    for (int r = 0; r < JR; ++r) {
        const int j = blockIdx.x * JB + jj + r * JJ;
        float k = 0.f, v1 = 0.f, v2 = 0.f, v3 = 0.f;
        if (j < M) {
            float2 xj = x[j];
            float  b  = bw[j];
            k  = -LOG2E / (2.0f * b * b);              // < 0
            v1 = -2.0f * k * xj.x;
            v2 = -2.0f * k * xj.y;
            v3 = k * fmaf(xj.x, xj.x, xj.y * xj.y);
        }
        c0p[r] = {k, k}; c1p[r] = {v1, v1}; c2p[r] = {v2, v2}; c3p[r] = {v3, v3};
    }

    f32x2 nump[JR], denp[JR];
    #pragma unroll
    for (int r = 0; r < JR; ++r) { nump[r] = {0.f, 0.f}; denp[r] = {0.f, 0.f}; }

    // register prefetch of chunk 0: thread t owns points (2t, 2t+1)
    const float4* in4  = (const float4*)inputs;   // 2 points per float4
    const float2* out2 = (const float2*)outputs;
    float4 pin  = make_float4(0.f, 0.f, 0.f, 0.f);
    float2 pout = make_float2(0.f, 0.f);
    if (2 * tid + 1 < N) { pin = in4[tid]; pout = out2[tid]; }

    for (int rep = 0; rep < REPS; ++rep) {
        for (int base = 0; base < N; base += CHUNK) {
            const int cnt = min(CHUNK, N - base);
            // stage pair (2t, 2t+1) -> row (2t)>>3, slots ((2t)&7, +1), b64 SoA writes
            {
                const int  r0 = tid >> 2;
                const int  s0 = (2 * tid) & (PTS - 1);
                const bool v0 = (2 * tid) < cnt;
                const bool v1 = (2 * tid + 1) < cnt;
                f32x2 xp = {v0 ? pin.x : 0.f, v1 ? pin.z : 0.f};
                f32x2 yp = {v0 ? pin.y : 0.f, v1 ? pin.w : 0.f};
                f32x2 sp = {v0 ? fmaf(pin.x, pin.x, pin.y * pin.y) : 3.0e38f,  // c0*s -> -inf -> w=0
                            v1 ? fmaf(pin.z, pin.z, pin.w * pin.w) : 3.0e38f};
                f32x2 op = {v0 ? pout.x : 0.f, v1 ? pout.y : 0.f};
                *(f32x2*)&sX[r0][s0] = xp;
                *(f32x2*)&sY[r0][s0] = yp;
                *(f32x2*)&sS[r0][s0] = sp;
                *(f32x2*)&sO[r0][s0] = op;
            }
            __syncthreads();

            // prefetch next chunk (wraps to chunk 0 across reps); flies under compute
            {
                int nb = base + CHUNK;
                if (nb >= N) nb = 0;
                const int i0 = (nb >> 1) + tid;
                if (2 * i0 + 1 < N) { pin = in4[i0]; pout = out2[i0]; }
            }

            // compute: PTS points as PTS/4 b128 groups x JR j's
            #pragma unroll
            for (int g = 0; g < PTS / 4; ++g) {
                f32x4 xq = *(const f32x4*)&sX[ss][4 * g];   // ds_read_b128, 2-way = free
                f32x4 yq = *(const f32x4*)&sY[ss][4 * g];
                f32x4 sq = *(const f32x4*)&sS[ss][4 * g];
                f32x4 oq = *(const f32x4*)&sO[ss][4 * g];
                f32x2 x0 = {xq.x, xq.y}, x1 = {xq.z, xq.w};
                f32x2 y0 = {yq.x, yq.y}, y1 = {yq.z, yq.w};
                f32x2 s0 = {sq.x, sq.y}, s1 = {sq.z, sq.w};
                f32x2 o0 = {oq.x, oq.y}, o1 = {oq.z, oq.w};
                #pragma unroll
                for (int r = 0; r < JR; ++r) {
                    f32x2 ta = __builtin_elementwise_fma(c2p[r], y0, c3p[r]);
                    ta = __builtin_elementwise_fma(c1p[r], x0, ta);
                    ta = __builtin_elementwise_fma(c0p[r], s0, ta);
                    f32x2 tb = __builtin_elementwise_fma(c2p[r], y1, c3p[r]);
                    tb = __builtin_elementwise_fma(c1p[r], x1, tb);
                    tb = __builtin_elementwise_fma(c0p[r], s1, tb);
                    f32x2 wa, wb;
                    wa.x = __builtin_amdgcn_exp2f(ta.x);
                    wa.y = __builtin_amdgcn_exp2f(ta.y);
                    wb.x = __builtin_amdgcn_exp2f(tb.x);
                    wb.y = __builtin_amdgcn_exp2f(tb.y);
                    nump[r] = __builtin_elementwise_fma(wa, o0, nump[r]);
                    nump[r] = __builtin_elementwise_fma(wb, o1, nump[r]);
                    denp[r] += wa + wb;
                }
            }
            __syncthreads();
        }
    }

    // two-stage block reduction across the 128 segments
    #pragma unroll
    for (int r = 0; r < JR; ++r)
        red[ss][jj + r * JJ] = make_float2(nump[r].x + nump[r].y,
                                           denp[r].x + denp[r].y);
    __syncthreads();
    if (tid < 16 * JB) {                 // 256 threads: (s2, slot)
        const int s2   = tid >> 4;       // 0..15
        const int slot = tid & 15;
        float n = 0.f, d = 0.f;
        #pragma unroll
        for (int k = 0; k < SS / 16; ++k) {
            n += red[s2 + 16 * k][slot].x;
            d += red[s2 + 16 * k][slot].y;
        }
        red[s2][slot] = make_float2(n, d);
    }
    __syncthreads();
    if (tid < JB) {
        float n = 0.f, d = 0.f;
        #pragma unroll
        for (int s = 0; s < 16; ++s) {
            n += red[s][tid].x;
            d += red[s][tid].y;
        }
        const int jo = blockIdx.x * JB + tid;
        if (jo < M) out[jo] = n / (d + EPS);
    }
}

extern "C" void kernel_launch(void* const* d_in, const int* in_sizes, int n_in,
                              void* d_out, int out_size, void* d_ws, size_t ws_size,
                              hipStream_t stream) {
    // setup_inputs() dict order: x (M*2), inputs (N*2), outputs (N), bandwidth (M)
    const float2* x       = (const float2*)d_in[0];
    const float2* inputs  = (const float2*)d_in[1];
    const float*  outputs = (const float*) d_in[2];
    const float*  bwv     = (const float*) d_in[3];
    const int N = in_sizes[2];   // outputs element count
    const int M = in_sizes[3];   // bandwidth element count
    float*        out     = (float*)d_out;

    dim3 grid((M + JB - 1) / JB);    // 512 blocks @ M=8192 -> 2 blocks/CU
    nw_block<<<grid, BLOCK, 0, stream>>>(x, inputs, outputs, bwv, out, N, M);
}